// Round 5
// baseline (521.211 us; speedup 1.0000x reference)
//
#include <hip/hip_runtime.h>
#include <stdint.h>

// Problem constants (fixed by the reference setup)
#define NB 32
#define NP 4096
#define NC 512
#define NK 16
#define CTILE 16            // concepts per block
#define NCG (NC / CTILE)    // 32 c-groups
#define CAP 192             // candidates/row: mean 93.2, sigma 9.5 -> +10 sigma; exact fallback anyway
#define FTHRESH 2.0f        // N(0,1): P(v>2.0)=0.02275 -> E[cand]=93 of 4096; 16th stat ~= 2.65
#define BLK 512             // 8 waves/block; 1024 blocks = 4 blk/CU * 8 = 32 waves/CU
#define PSTRIDE (BLK / 4)   // 128 patches per load slice
#define DEPTH 4             // loads in flight per thread (explicit batching)

// Monotone float->u32 transform (order-preserving)
__device__ __forceinline__ uint32_t ord32(float f) {
  uint32_t u = __float_as_uint(f);
  return (u & 0x80000000u) ? ~u : (u | 0x80000000u);
}
__device__ __forceinline__ float unord32(uint32_t o) {
  uint32_t u = (o & 0x80000000u) ? (o ^ 0x80000000u) : ~o;
  return __uint_as_float(u);
}

// Butterfly max over all 64 lanes (fallback path only).
__device__ __forceinline__ unsigned long long waveMax64(unsigned long long v) {
  #pragma unroll
  for (int off = 32; off > 0; off >>= 1) {
    unsigned long long o = __shfl_xor(v, off, 64);
    v = (o > v) ? o : v;
  }
  return v;
}

__global__ __launch_bounds__(BLK, 8) void topk_pool_kernel(
    const float* __restrict__ sim, float* __restrict__ out) {
  __shared__ unsigned long long cand[CTILE][CAP];  // 24 KB; 4 blocks/CU = 100 KB < 160 KB
  __shared__ unsigned int cnt[CTILE];

  const int b  = blockIdx.x >> 5;   // NCG = 32
  const int cg = blockIdx.x & 31;
  const int c0 = cg * CTILE;
  const float* simBase = sim + ((size_t)b * NP * NC + c0);
  float* maskBase = out + (size_t)NB * NC + ((size_t)b * NP * NC + c0);
  float* scoreRow = out + (size_t)b * NC;

  const int tid = threadIdx.x;
  // Zero-init candidate slots: key 0 < every real key (real keys have ord32 of
  // a positive float in the high word) -> padding never ranks, no guards needed.
  {
    unsigned long long* cl = &cand[0][0];
    #pragma unroll
    for (int j = 0; j < (CTILE * CAP) / BLK; ++j) cl[tid + BLK * j] = 0ull;
    if (tid < CTILE) cnt[tid] = 0u;
  }
  __syncthreads();

  // ---- Pass A+B fused, DEPTH-deep explicit load batching.
  // Issue DEPTH strided float4 loads + DEPTH zero-stores in ONE basic block
  // (no branches) so the scheduler keeps them all in flight; THEN run the
  // branchy candidate filter on the registered values. This is the MLP fix:
  // previous build had VGPR=28 => ~1 load in flight (branches blocked
  // cross-iteration hoisting) => latency-bound at 2.5 TB/s.
  // key = (ord(value) << 32) | (NP-1-p): larger key == (value desc, index asc),
  // exactly lax.top_k's tie-break. Keys unique per row (p unique).
  {
    const int q4 = (tid & 3) << 2;       // concept quartet within the 16-row tile
    const int p0 = tid >> 2;             // starting patch 0..127
    const float* src0 = simBase + (size_t)p0 * NC + q4;
    float* dst0 = maskBase + (size_t)p0 * NC + q4;
    const float4 z4 = make_float4(0.f, 0.f, 0.f, 0.f);
    constexpr size_t SL = (size_t)PSTRIDE * NC;   // slice stride in floats

    #pragma unroll 1
    for (int it = 0; it < NP / (DEPTH * PSTRIDE); ++it) {  // 8 iterations
      const float* s = src0 + (size_t)it * DEPTH * SL;
      float* d = dst0 + (size_t)it * DEPTH * SL;
      // -- load/store block: 4 independent loads + 4 independent stores
      const float4 v0 = *reinterpret_cast<const float4*>(s);
      const float4 v1 = *reinterpret_cast<const float4*>(s + SL);
      const float4 v2 = *reinterpret_cast<const float4*>(s + 2 * SL);
      const float4 v3 = *reinterpret_cast<const float4*>(s + 3 * SL);
      *reinterpret_cast<float4*>(d) = z4;
      *reinterpret_cast<float4*>(d + SL) = z4;
      *reinterpret_cast<float4*>(d + 2 * SL) = z4;
      *reinterpret_cast<float4*>(d + 3 * SL) = z4;
      // -- filter block (branchy, rare hits)
      const int pb = p0 + it * DEPTH * PSTRIDE;
      const float4 vs[DEPTH] = {v0, v1, v2, v3};
      #pragma unroll
      for (int dd = 0; dd < DEPTH; ++dd) {
        const int p = pb + dd * PSTRIDE;
        const float vv[4] = {vs[dd].x, vs[dd].y, vs[dd].z, vs[dd].w};
        #pragma unroll
        for (int k = 0; k < 4; ++k) {
          if (vv[k] > FTHRESH) {
            const unsigned long long key =
                ((unsigned long long)ord32(vv[k]) << 32) | (unsigned)(NP - 1 - p);
            const unsigned idx = atomicAdd(&cnt[q4 + k], 1u);
            if (idx < CAP) cand[q4 + k][idx] = key;
          }
        }
      }
    }
  }

  __syncthreads();  // drains zero-stores (vmcnt 0) + makes cand/cnt visible

  // ---- Pass C: rank-count selection, one wave per row (2 rows/wave), no
  // serialized rounds. Each lane holds 3 keys; rank = #{row keys > mine};
  // rank<NK -> top-16 member.
  const int wave = tid >> 6;           // 0..7
  const int lane = tid & 63;

  #pragma unroll 1
  for (int rr = 0; rr < CTILE / 8; ++rr) {
    const int r = wave + (rr << 3);
    const unsigned n = cnt[r];
    if (n >= NK && n <= CAP) {
      const unsigned long long kv0 = cand[r][lane];
      const unsigned long long kv1 = cand[r][lane + 64];
      const unsigned long long kv2 = cand[r][lane + 128];
      int rk0 = 0, rk1 = 0, rk2 = 0;
      const unsigned nn = (n + 1u) & ~1u;  // slot n is zero-padded if n odd
      for (unsigned t = 0; t < nn; t += 2) {
        // broadcast b128 read: all lanes same address, conflict-free
        const unsigned long long Ka = cand[r][t];
        const unsigned long long Kb = cand[r][t + 1];
        rk0 += (Ka > kv0) + (Kb > kv0);
        rk1 += (Ka > kv1) + (Kb > kv1);
        rk2 += (Ka > kv2) + (Kb > kv2);
      }
      // zero keys rank >= n >= 16, auto-excluded
      if (rk0 < NK) {
        const int p = NP - 1 - (int)(kv0 & 0xFFFFFFFFull);
        maskBase[(size_t)p * NC + r] = 1.0f;
        if (rk0 == 0) scoreRow[c0 + r] = unord32((uint32_t)(kv0 >> 32));
      }
      if (rk1 < NK) {
        const int p = NP - 1 - (int)(kv1 & 0xFFFFFFFFull);
        maskBase[(size_t)p * NC + r] = 1.0f;
        if (rk1 == 0) scoreRow[c0 + r] = unord32((uint32_t)(kv1 >> 32));
      }
      if (rk2 < NK) {
        const int p = NP - 1 - (int)(kv2 & 0xFFFFFFFFull);
        maskBase[(size_t)p * NC + r] = 1.0f;
        if (rk2 == 0) scoreRow[c0 + r] = unord32((uint32_t)(kv2 >> 32));
      }
    } else {
      // exact fallback (candidate under/overflow; statistically never taken):
      // 16 rounds of strict descending extraction straight from global (L2-warm).
      unsigned long long prev = ~0ull;
      #pragma unroll 1
      for (int round = 0; round < NK; ++round) {
        unsigned long long loc = 0ull;
        for (int p = lane; p < NP; p += 64) {
          const float v = simBase[(size_t)p * NC + r];
          const unsigned long long key =
              ((unsigned long long)ord32(v) << 32) | (unsigned)(NP - 1 - p);
          if (key < prev && key > loc) loc = key;
        }
        const unsigned long long m = waveMax64(loc);
        if (lane == 0) {
          const int p = NP - 1 - (int)(m & 0xFFFFFFFFull);
          maskBase[(size_t)p * NC + r] = 1.0f;
          if (round == 0) scoreRow[c0 + r] = unord32((uint32_t)(m >> 32));
        }
        prev = m;
      }
    }
  }
}

extern "C" void kernel_launch(void* const* d_in, const int* in_sizes, int n_in,
                              void* d_out, int out_size, void* d_ws, size_t ws_size,
                              hipStream_t stream) {
  const float* sim = (const float*)d_in[0];
  float* out = (float*)d_out;
  hipLaunchKernelGGL(topk_pool_kernel, dim3(NB * NCG), dim3(BLK), 0, stream,
                     sim, out);
}

// Round 7
// 484.262 us; speedup vs baseline: 1.0763x; 1.0763x over previous
//
#include <hip/hip_runtime.h>
#include <stdint.h>

// Problem constants (fixed by the reference setup)
#define NB 32
#define NP 4096
#define NC 512
#define NK 16
#define CTILE 32            // concepts per block: 32 -> each patch-row segment = 128 B (full L2 line)
#define NCG (NC / CTILE)    // 16 c-groups
#define CAP 192             // candidates/row: mean 93.2, sigma 9.5 -> +10 sigma; exact fallback anyway
#define FTHRESH 2.0f        // N(0,1): P(v>2.0)=0.02275 -> E[cand]=93 of 4096; 16th stat ~= 2.65
#define BLK 512             // 8 waves/block; 512 blocks = 2 blk/CU * 8 = 16 waves/CU

// Monotone float->u32 transform (order-preserving)
__device__ __forceinline__ uint32_t ord32(float f) {
  uint32_t u = __float_as_uint(f);
  return (u & 0x80000000u) ? ~u : (u | 0x80000000u);
}
__device__ __forceinline__ float unord32(uint32_t o) {
  uint32_t u = (o & 0x80000000u) ? (o ^ 0x80000000u) : ~o;
  return __uint_as_float(u);
}

// Butterfly max over all 64 lanes (fallback path only).
__device__ __forceinline__ unsigned long long waveMax64(unsigned long long v) {
  #pragma unroll
  for (int off = 32; off > 0; off >>= 1) {
    unsigned long long o = __shfl_xor(v, off, 64);
    v = (o > v) ? o : v;
  }
  return v;
}

__global__ __launch_bounds__(BLK) void topk_pool_kernel(
    const float* __restrict__ sim, float* __restrict__ out) {
  __shared__ unsigned long long cand[CTILE][CAP];  // 48 KB; 2 blocks/CU = 96 KB < 160 KB
  __shared__ unsigned int cnt[CTILE];

  const int b  = blockIdx.x >> 4;   // NCG = 16
  const int cg = blockIdx.x & 15;
  const int c0 = cg * CTILE;
  const float* simBase = sim + ((size_t)b * NP * NC + c0);
  float* maskBase = out + (size_t)NB * NC + ((size_t)b * NP * NC + c0);
  float* scoreRow = out + (size_t)b * NC;

  const int tid = threadIdx.x;
  // Zero-init candidate slots: key 0 < every real key (real keys have ord32 of
  // a positive float in the high word) -> padding never ranks, no guards needed.
  {
    unsigned long long* cl = &cand[0][0];
    #pragma unroll
    for (int j = 0; j < (CTILE * CAP) / BLK; ++j) cl[tid + BLK * j] = 0ull;
    if (tid < CTILE) cnt[tid] = 0u;
  }
  __syncthreads();

  // ---- Pass A+B fused: stream input tile AND zero-fill mask tile.
  // Memory-request shape is the whole point of this revision: 8 lanes x
  // float4 = 128 B fully-used line per patch row (was 64 B with CTILE=16).
  // Per-CU outstanding-request queue then moves 2x the bytes per entry.
  // key = (ord(value) << 32) | (NP-1-p): larger key == (value desc, index asc),
  // exactly lax.top_k's tie-break. Keys unique per row (p unique).
  {
    const int q4 = (tid & 7) << 2;       // concept quartet within the 32-row tile
    int p = tid >> 3;                    // starting patch 0..63, stride 64
    const float* src = simBase + (size_t)p * NC + q4;
    float* dst = maskBase + (size_t)p * NC + q4;
    const float4 z4 = make_float4(0.f, 0.f, 0.f, 0.f);
    #pragma unroll 4
    for (int it = 0; it < NP / (BLK / 8); ++it) {   // 64 iterations
      const float4 v = *reinterpret_cast<const float4*>(src);
      *reinterpret_cast<float4*>(dst) = z4;
      const float vv[4] = {v.x, v.y, v.z, v.w};
      #pragma unroll
      for (int k = 0; k < 4; ++k) {
        if (vv[k] > FTHRESH) {
          const unsigned long long key =
              ((unsigned long long)ord32(vv[k]) << 32) | (unsigned)(NP - 1 - p);
          const unsigned idx = atomicAdd(&cnt[q4 + k], 1u);
          if (idx < CAP) cand[q4 + k][idx] = key;
        }
      }
      p += BLK / 8;
      src += (size_t)(BLK / 8) * NC;
      dst += (size_t)(BLK / 8) * NC;
    }
  }

  __syncthreads();  // drains zero-stores (vmcnt 0) + makes cand/cnt visible

  // ---- Pass C: rank-count selection, one wave per row (4 rows/wave), no
  // serialized rounds. Each lane holds 3 keys; rank = #{row keys > mine};
  // rank<NK -> top-16 member.
  const int wave = tid >> 6;           // 0..7
  const int lane = tid & 63;

  #pragma unroll 1
  for (int rr = 0; rr < CTILE / 8; ++rr) {
    const int r = wave + (rr << 3);
    const unsigned n = cnt[r];
    if (n >= NK && n <= CAP) {
      const unsigned long long kv0 = cand[r][lane];
      const unsigned long long kv1 = cand[r][lane + 64];
      const unsigned long long kv2 = cand[r][lane + 128];
      int rk0 = 0, rk1 = 0, rk2 = 0;
      const unsigned nn = (n + 1u) & ~1u;  // slot n is zero-padded if n odd
      for (unsigned t = 0; t < nn; t += 2) {
        // broadcast b128 read: all lanes same address, conflict-free
        const unsigned long long Ka = cand[r][t];
        const unsigned long long Kb = cand[r][t + 1];
        rk0 += (Ka > kv0) + (Kb > kv0);
        rk1 += (Ka > kv1) + (Kb > kv1);
        rk2 += (Ka > kv2) + (Kb > kv2);
      }
      // zero keys rank >= n >= 16, auto-excluded
      if (rk0 < NK) {
        const int p = NP - 1 - (int)(kv0 & 0xFFFFFFFFull);
        maskBase[(size_t)p * NC + r] = 1.0f;
        if (rk0 == 0) scoreRow[c0 + r] = unord32((uint32_t)(kv0 >> 32));
      }
      if (rk1 < NK) {
        const int p = NP - 1 - (int)(kv1 & 0xFFFFFFFFull);
        maskBase[(size_t)p * NC + r] = 1.0f;
        if (rk1 == 0) scoreRow[c0 + r] = unord32((uint32_t)(kv1 >> 32));
      }
      if (rk2 < NK) {
        const int p = NP - 1 - (int)(kv2 & 0xFFFFFFFFull);
        maskBase[(size_t)p * NC + r] = 1.0f;
        if (rk2 == 0) scoreRow[c0 + r] = unord32((uint32_t)(kv2 >> 32));
      }
    } else {
      // exact fallback (candidate under/overflow; statistically never taken):
      // 16 rounds of strict descending extraction straight from global (L2-warm).
      unsigned long long prev = ~0ull;
      #pragma unroll 1
      for (int round = 0; round < NK; ++round) {
        unsigned long long loc = 0ull;
        for (int p = lane; p < NP; p += 64) {
          const float v = simBase[(size_t)p * NC + r];
          const unsigned long long key =
              ((unsigned long long)ord32(v) << 32) | (unsigned)(NP - 1 - p);
          if (key < prev && key > loc) loc = key;
        }
        const unsigned long long m = waveMax64(loc);
        if (lane == 0) {
          const int p = NP - 1 - (int)(m & 0xFFFFFFFFull);
          maskBase[(size_t)p * NC + r] = 1.0f;
          if (round == 0) scoreRow[c0 + r] = unord32((uint32_t)(m >> 32));
        }
        prev = m;
      }
    }
  }
}

extern "C" void kernel_launch(void* const* d_in, const int* in_sizes, int n_in,
                              void* d_out, int out_size, void* d_ws, size_t ws_size,
                              hipStream_t stream) {
  const float* sim = (const float*)d_in[0];
  float* out = (float*)d_out;
  hipLaunchKernelGGL(topk_pool_kernel, dim3(NB * NCG), dim3(BLK), 0, stream,
                     sim, out);
}